// Round 10
// baseline (119.998 us; speedup 1.0000x reference)
//
#include <hip/hip_runtime.h>

#define VQ_EPS    1e-12f
#define VQ_WINDOW 0.01f     // >= ~14 sigma of the bf16 score error; proven R6-R10 (absmax 0)
#define VQ_CAP    12

typedef short bf16x8 __attribute__((ext_vector_type(8)));   // 8 bf16 bit-patterns = 4 VGPRs
typedef float f32x4  __attribute__((ext_vector_type(4)));

static __device__ __forceinline__ unsigned short f2bf(float f) {
    unsigned u = __float_as_uint(f);
    u += 0x7fffu + ((u >> 16) & 1u);     // RNE
    return (unsigned short)(u >> 16);
}

// Order-preserving float->uint map (handles negative exact scores).
static __device__ __forceinline__ unsigned f2ord(float f) {
    unsigned b = __float_as_uint(f);
    return (b & 0x80000000u) ? ~b : (b | 0x80000000u);
}

// Wave-local LDS fence (proven R14, absmax 0): drains this wave's DS ops and
// stops compiler reordering. Sufficient for slot traffic produced AND
// consumed by the same wave.
static __device__ __forceinline__ void wave_lds_fence() {
    asm volatile("s_waitcnt lgkmcnt(0)" ::: "memory");
}

// Single-instruction median (VOP3 v_med3_u32, GCN3+/gfx950).
static __device__ __forceinline__ unsigned umed3(unsigned a, unsigned b, unsigned c) {
    unsigned d;
    asm("v_med3_u32 %0, %1, %2, %3" : "=v"(d) : "v"(a), "v"(b), "v"(c));
    return d;
}

// Prep kernel: normalize codebook rows (fp32, mirrors F.normalize), emit:
//   cbn  [512][64] fp32      -- exact rescore + codes-gather epilogue
//   cbB  [32 ntile][2 kstep][64 lane][8] bf16 -- B-fragment-linear for
//        mfma_f32_16x16x32_bf16 (layout proven correct R5-R10)
//   kn2  [512] fp32          -- sum(cbn^2) AFTER normalization (reference rounding)
//   kn2p [512] fp32          -- kn2 + 2.0f (keeps approx scores > 0 for uint packing)
__global__ __launch_bounds__(64) void cb_prep_kernel(const float* __restrict__ cb,
                                                     float* __restrict__ cbn,
                                                     unsigned short* __restrict__ cbB,
                                                     float* __restrict__ kn2,
                                                     float* __restrict__ kn2p) {
    const int k = blockIdx.x;       // 512 codes
    const int c = threadIdx.x;      // 64 channels
    float v = cb[k * 64 + c];
    float s = v * v;
    #pragma unroll
    for (int off = 32; off > 0; off >>= 1) s += __shfl_xor(s, off, 64);
    float n = sqrtf(s);
    float cn = v / fmaxf(n, VQ_EPS);
    cbn[k * 64 + c] = cn;

    const int ntile = k >> 4, col = k & 15;
    const int ks = c >> 5, quad = (c >> 3) & 3, j = c & 7;
    cbB[(((ntile * 2 + ks) * 64) + quad * 16 + col) * 8 + j] = f2bf(cn);

    float s2 = cn * cn;
    #pragma unroll
    for (int off = 32; off > 0; off >>= 1) s2 += __shfl_xor(s2, off, 64);
    if (c == 0) { kn2[k] = s2; kn2p[k] = s2 + 2.0f; }
}

// ===========================================================================
// R20 K1: scan kernel. R19's front half (gather + staging + MFMA top-3 scan
// + candidate collect), exporting per-pixel {cnt, m2, cand[<=12]} to global
// workspace instead of running rescore/epilogue in-line. Waves exit right
// after collect -- no rescore-latency or write-drain convoy inside the
// scan dispatch; the finish kernel overlaps its own phases at high
// occupancy. All scoring machinery is R19 verbatim (proven absmax 0).
// ===========================================================================
__global__ __launch_bounds__(1024, 8) void vq_scan_kernel(const float* __restrict__ x,
                                                      const unsigned short* __restrict__ cbB,
                                                      const float* __restrict__ kn2p,
                                                      int* __restrict__ pcnt,
                                                      float* __restrict__ pm2,
                                                      unsigned short* __restrict__ pcand) {
    __shared__ __align__(16) unsigned short lcb[32768];   // 64 KB staged cbB
    __shared__ int slist[256][VQ_CAP];                    // 12 KB
    __shared__ int scnt[256];                             // 1 KB   -> 77 KB total

    const int t    = threadIdx.x;
    const int lane = t & 63;
    const int wid  = t >> 6;          // 0..15
    const int col  = lane & 15;
    const int quad = lane >> 4;
    const int wr   = wid & 3;         // wave within its row
    const int rsel = wid >> 2;        // which of the block's 4 rows
    const int wpix = wr * 16 + col;   // col-group's pixel (w coordinate)
    const int pbase = rsel * 64;      // LDS pixel-slot base for this row
    const int pslot = pbase + wpix;

    const int rowid = blockIdx.x * 4 + rsel;   // 0..2047 = (b,h)
    const int b = rowid >> 6;
    const int h = rowid & 63;
    const float* xblk = x + ((size_t)b << 18) + (h << 6);   // + c*4096 + w

    if (quad == 0) scnt[pslot] = 0;

    // ---- A fragments: 16 channels of this lane's pixel, from global ----
    float xv[16];
    #pragma unroll
    for (int ks = 0; ks < 2; ++ks)
        #pragma unroll
        for (int j = 0; j < 8; ++j)
            xv[ks * 8 + j] = xblk[(size_t)(ks * 32 + quad * 8 + j) * 4096 + wpix];

    // ---- stage cbB -> LDS: 1024 thr x 4 x 16 B, linear, coalesced ----
    {
        const uint4* g4 = (const uint4*)cbB;
        uint4*       l4 = (uint4*)lcb;
        #pragma unroll
        for (int r = 0; r < 4; ++r) l4[r * 1024 + t] = g4[r * 1024 + t];
    }

    float ssp = 0.0f;
    #pragma unroll
    for (int i = 0; i < 16; ++i) ssp = fmaf(xv[i], xv[i], ssp);
    ssp += __shfl_xor(ssp, 16);      // uniform code: all 64 lanes execute
    ssp += __shfl_xor(ssp, 32);
    const float m2a = -2.0f * (1.0f / fmaxf(sqrtf(ssp), VQ_EPS));
    float m2r[4];
    #pragma unroll
    for (int r = 0; r < 4; ++r) m2r[r] = __shfl(m2a, quad * 4 + r);  // uniform

    bf16x8 afrag[2];
    #pragma unroll
    for (int ks = 0; ks < 2; ++ks)
        #pragma unroll
        for (int j = 0; j < 8; ++j)
            ((unsigned short*)&afrag[ks])[j] = f2bf(xv[ks * 8 + j]);

    __syncthreads();   // B0: staged cbB (and slot init) visible to all 16 waves

    const bf16x8* lBf = (const bf16x8*)lcb;

    // ---- pass 1: MFMA scan from LDS, sorted top-3 keys per (lane,r) slot ----
    unsigned run1[4] = {0xFFFFFFFFu, 0xFFFFFFFFu, 0xFFFFFFFFu, 0xFFFFFFFFu};
    unsigned run2[4] = {0xFFFFFFFFu, 0xFFFFFFFFu, 0xFFFFFFFFu, 0xFFFFFFFFu};
    unsigned run3[4] = {0xFFFFFFFFu, 0xFFFFFFFFu, 0xFFFFFFFFu, 0xFFFFFFFFu};
    #pragma unroll 4
    for (int nt = 0; nt < 32; ++nt) {
        bf16x8 b0 = lBf[(nt * 2 + 0) * 64 + lane];     // ds_read_b128, conflict-free
        bf16x8 b1 = lBf[(nt * 2 + 1) * 64 + lane];
        f32x4 c = {0.0f, 0.0f, 0.0f, 0.0f};
        c = __builtin_amdgcn_mfma_f32_16x16x32_bf16(afrag[0], b0, c, 0, 0, 0);
        c = __builtin_amdgcn_mfma_f32_16x16x32_bf16(afrag[1], b1, c, 0, 0, 0);
        const float    kn   = kn2p[nt * 16 + col];     // L1-hot
        const unsigned kidx = (unsigned)(nt * 16 + col);
        #pragma unroll
        for (int r = 0; r < 4; ++r) {
            float s = fmaf(m2r[r], c[r], kn);          // (~0.6, 5.2) -> uint-orderable
            unsigned key = (__float_as_uint(s) & 0xFFFFFE00u) | kidx;  // 9-bit k field
            unsigned o1 = run1[r], o2 = run2[r];
            run1[r] = min(o1, key);
            run2[r] = umed3(o1, key, o2);              // sorted-insert rank 2
            run3[r] = umed3(o2, key, run3[r]);         // sorted-insert rank 3
        }
    }

    // ---- thresholds: cross-lane min within each 16-lane col group (uniform) ----
    float thr[4];
    #pragma unroll
    for (int r = 0; r < 4; ++r) {
        unsigned v = run1[r];
        v = min(v, (unsigned)__shfl_xor((int)v, 1));
        v = min(v, (unsigned)__shfl_xor((int)v, 2));
        v = min(v, (unsigned)__shfl_xor((int)v, 4));
        v = min(v, (unsigned)__shfl_xor((int)v, 8));
        thr[r] = __uint_as_float(v & 0xFFFFFE00u) + VQ_WINDOW;
    }

    // ---- wave flag: any slot whose 3rd-best is within threshold? (uniform) ----
    bool f = false;
    #pragma unroll
    for (int r = 0; r < 4; ++r)
        f |= (__uint_as_float(run3[r] & 0xFFFFFE00u) <= thr[r]);
    const unsigned long long waveflag = __ballot(f);   // uniform code

    if (waveflag != 0ull) {
        // ---- fallback pass 2 (rare): bit-identical full recompute ----
        #pragma unroll 4
        for (int nt = 0; nt < 32; ++nt) {
            bf16x8 b0 = lBf[(nt * 2 + 0) * 64 + lane];
            bf16x8 b1 = lBf[(nt * 2 + 1) * 64 + lane];
            f32x4 c = {0.0f, 0.0f, 0.0f, 0.0f};
            c = __builtin_amdgcn_mfma_f32_16x16x32_bf16(afrag[0], b0, c, 0, 0, 0);
            c = __builtin_amdgcn_mfma_f32_16x16x32_bf16(afrag[1], b1, c, 0, 0, 0);
            const float kn   = kn2p[nt * 16 + col];
            const int   kidx = nt * 16 + col;
            #pragma unroll
            for (int r = 0; r < 4; ++r) {
                float s = fmaf(m2r[r], c[r], kn);
                if (s <= thr[r]) {
                    int pix = pbase + wr * 16 + quad * 4 + r;   // wave-owned pixel
                    int pos = atomicAdd(&scnt[pix], 1);
                    if (pos < VQ_CAP) slist[pix][pos] = kidx;
                }
            }
        }
    } else {
        // ---- fast path: push in-window ranks 1 AND 2 from registers ----
        #pragma unroll
        for (int r = 0; r < 4; ++r) {
            float s1 = __uint_as_float(run1[r] & 0xFFFFFE00u);
            if (s1 <= thr[r]) {
                int pix = pbase + wr * 16 + quad * 4 + r;       // wave-owned pixel
                int pos = atomicAdd(&scnt[pix], 1);
                if (pos < VQ_CAP) slist[pix][pos] = (int)(run1[r] & 0x1FFu);
            }
            float s2 = __uint_as_float(run2[r] & 0xFFFFFE00u);
            if (s2 <= thr[r]) {
                int pix = pbase + wr * 16 + quad * 4 + r;
                int pos = atomicAdd(&scnt[pix], 1);
                if (pos < VQ_CAP) slist[pix][pos] = (int)(run2[r] & 0x1FFu);
            }
        }
    }
    wave_lds_fence();   // slot traffic above is same-wave only

    // ---- export per-pixel state: {cnt, m2, cand[<=12]} (quad==0 lanes own
    //      their pixel wpix; slot data is same-wave, fence above) ----
    if (quad == 0) {
        const int gpix = rowid * 64 + wpix;
        const int cnt  = scnt[pslot];
        pcnt[gpix] = cnt;
        pm2[gpix]  = m2a;               // this lane's pixel norm factor
        const int m = min(cnt, VQ_CAP);
        unsigned short* pc = pcand + (size_t)gpix * VQ_CAP;
        for (int i = 0; i < m; ++i) pc[i] = (unsigned short)slist[pslot][i];
    }
}

// ===========================================================================
// R20 K2: finish kernel. 2048 blocks x 256 thr (4 waves, 16 px/wave).
// Per pixel: cnt==1 -> winner = cand[0] (no rescore); 1<cnt<=CAP -> exact
// fp32 rescore of the list; cnt>CAP -> exact 512-scan. Rescore is the
// proven machinery verbatim: 4-lane teams, per-lane serial fmaf in R1
// channel order, packed-key atomicMin tie-break (smallest k on ties).
// Epilogue identical shape to R19 (4-lane float4 cbn gather, coalesced
// channel scatter). Tiny LDS -> high occupancy, latency-tolerant.
// ===========================================================================
__global__ __launch_bounds__(256) void vq_finish_kernel(const float* __restrict__ x,
                                                      const float* __restrict__ cbn,
                                                      const float* __restrict__ kn2,
                                                      const int* __restrict__ pcnt,
                                                      const float* __restrict__ pm2,
                                                      const unsigned short* __restrict__ pcand,
                                                      float* __restrict__ codes,
                                                      float* __restrict__ idxout) {
    __shared__ unsigned long long spack[64];

    const int t    = threadIdx.x;
    const int lane = t & 63;
    const int wid  = t >> 6;               // 0..3
    const int col  = lane & 15;
    const int quad = lane >> 4;
    const int gbase = (blockIdx.x * 4 + wid) * 16;   // this wave's 16 pixels
    const int pslot = wid * 16 + col;                // epilogue pixel's LDS slot

    if (quad == 0) spack[pslot] = 0xFFFFFFFFFFFFFFFFull;

    // ---- exact fp32 rescore: 4 lanes/pixel, per-lane only ----
    {
        const int gp   = gbase + (lane >> 2);        // rescore pixel (global id)
        const int sub  = lane & 3;
        const int slot = wid * 16 + (lane >> 2);
        const int cnt  = pcnt[gp];
        if (cnt > 1) {
            const float m2P = pm2[gp];
            const int w = gp & 63, rowid = gp >> 6;
            const int b = rowid >> 6, h = rowid & 63;
            const float* xp = x + ((size_t)b << 18) + (h << 6) + w;
            if (cnt <= VQ_CAP) {
                const unsigned short* pc = pcand + (size_t)gp * VQ_CAP;
                for (int i = sub; i < cnt; i += 4) {
                    const int k = pc[i];
                    const float* cr = cbn + (size_t)k * 64;
                    float dot = 0.0f;
                    #pragma unroll 8
                    for (int c = 0; c < 64; ++c)
                        dot = fmaf(xp[(size_t)c * 4096], cr[c], dot);  // R1 order
                    float s = fmaf(m2P, dot, kn2[k]);
                    unsigned long long key =
                        ((unsigned long long)f2ord(s) << 32) | (unsigned)k;
                    atomicMin(&spack[slot], key);
                }
            } else {   // pathological overflow: exact scan of all codes
                for (int k = sub; k < 512; k += 4) {
                    const float* cr = cbn + (size_t)k * 64;
                    float dot = 0.0f;
                    #pragma unroll 8
                    for (int c = 0; c < 64; ++c)
                        dot = fmaf(xp[(size_t)c * 4096], cr[c], dot);
                    float s = fmaf(m2P, dot, kn2[k]);
                    unsigned long long key =
                        ((unsigned long long)f2ord(s) << 32) | (unsigned)k;
                    atomicMin(&spack[slot], key);
                }
            }
        }
    }
    wave_lds_fence();   // spack init + atomics are same-wave (slots derive from wid)

    // ---- winner (cnt==1 fast path) + epilogue ----
    const int gp_e = gbase + col;
    const int cntw = pcnt[gp_e];
    const int bk = (cntw == 1) ? (int)pcand[(size_t)gp_e * VQ_CAP]
                               : (int)(spack[pslot] & 0xFFFFFFFFull);

    if (quad == 0) idxout[gp_e] = (float)bk;

    {
        const int w = gp_e & 63, rowid = gp_e >> 6;
        const int b = rowid >> 6, h = rowid & 63;
        const float4* crow = (const float4*)(cbn + (size_t)bk * 64) + quad * 4;
        float* cp = codes + ((size_t)b << 18) + (h << 6) + w;
        #pragma unroll
        for (int q = 0; q < 4; ++q) {
            float4 v = crow[q];
            const int c0 = quad * 16 + q * 4;
            cp[(size_t)(c0 + 0) * 4096] = v.x;
            cp[(size_t)(c0 + 1) * 4096] = v.y;
            cp[(size_t)(c0 + 2) * 4096] = v.z;
            cp[(size_t)(c0 + 3) * 4096] = v.w;
        }
    }
}

// ===========================================================================
// Fallback: R19 single-kernel (proven 46-50 us, absmax 0) -- used only if
// the workspace is too small for the split's per-pixel state (~4.3 MB).
// ===========================================================================
__global__ __launch_bounds__(1024, 8) void vq_mfma_kernel(const float* __restrict__ x,
                                                      const float* __restrict__ cbn,
                                                      const unsigned short* __restrict__ cbB,
                                                      const float* __restrict__ kn2,
                                                      const float* __restrict__ kn2p,
                                                      float* __restrict__ codes,
                                                      float* __restrict__ idxout) {
    __shared__ __align__(16) unsigned short lcb[32768];
    __shared__ unsigned long long spack[256];
    __shared__ int slist[256][VQ_CAP];
    __shared__ int scnt[256];

    const int t    = threadIdx.x;
    const int lane = t & 63;
    const int wid  = t >> 6;
    const int col  = lane & 15;
    const int quad = lane >> 4;
    const int wr   = wid & 3;
    const int rsel = wid >> 2;
    const int wpix = wr * 16 + col;
    const int pbase = rsel * 64;
    const int pslot = pbase + wpix;

    const int rowid = blockIdx.x * 4 + rsel;
    const int b = rowid >> 6;
    const int h = rowid & 63;
    const float* xblk = x + ((size_t)b << 18) + (h << 6);

    if (quad == 0) { scnt[pslot] = 0; spack[pslot] = 0xFFFFFFFFFFFFFFFFull; }

    float xv[16];
    #pragma unroll
    for (int ks = 0; ks < 2; ++ks)
        #pragma unroll
        for (int j = 0; j < 8; ++j)
            xv[ks * 8 + j] = xblk[(size_t)(ks * 32 + quad * 8 + j) * 4096 + wpix];

    {
        const uint4* g4 = (const uint4*)cbB;
        uint4*       l4 = (uint4*)lcb;
        #pragma unroll
        for (int r = 0; r < 4; ++r) l4[r * 1024 + t] = g4[r * 1024 + t];
    }

    float ssp = 0.0f;
    #pragma unroll
    for (int i = 0; i < 16; ++i) ssp = fmaf(xv[i], xv[i], ssp);
    ssp += __shfl_xor(ssp, 16);
    ssp += __shfl_xor(ssp, 32);
    const float m2a = -2.0f * (1.0f / fmaxf(sqrtf(ssp), VQ_EPS));
    float m2r[4];
    #pragma unroll
    for (int r = 0; r < 4; ++r) m2r[r] = __shfl(m2a, quad * 4 + r);
    const float m2P = __shfl(m2a, lane >> 2);

    bf16x8 afrag[2];
    #pragma unroll
    for (int ks = 0; ks < 2; ++ks)
        #pragma unroll
        for (int j = 0; j < 8; ++j)
            ((unsigned short*)&afrag[ks])[j] = f2bf(xv[ks * 8 + j]);

    __syncthreads();

    const bf16x8* lBf = (const bf16x8*)lcb;

    unsigned run1[4] = {0xFFFFFFFFu, 0xFFFFFFFFu, 0xFFFFFFFFu, 0xFFFFFFFFu};
    unsigned run2[4] = {0xFFFFFFFFu, 0xFFFFFFFFu, 0xFFFFFFFFu, 0xFFFFFFFFu};
    unsigned run3[4] = {0xFFFFFFFFu, 0xFFFFFFFFu, 0xFFFFFFFFu, 0xFFFFFFFFu};
    #pragma unroll 4
    for (int nt = 0; nt < 32; ++nt) {
        bf16x8 b0 = lBf[(nt * 2 + 0) * 64 + lane];
        bf16x8 b1 = lBf[(nt * 2 + 1) * 64 + lane];
        f32x4 c = {0.0f, 0.0f, 0.0f, 0.0f};
        c = __builtin_amdgcn_mfma_f32_16x16x32_bf16(afrag[0], b0, c, 0, 0, 0);
        c = __builtin_amdgcn_mfma_f32_16x16x32_bf16(afrag[1], b1, c, 0, 0, 0);
        const float    kn   = kn2p[nt * 16 + col];
        const unsigned kidx = (unsigned)(nt * 16 + col);
        #pragma unroll
        for (int r = 0; r < 4; ++r) {
            float s = fmaf(m2r[r], c[r], kn);
            unsigned key = (__float_as_uint(s) & 0xFFFFFE00u) | kidx;
            unsigned o1 = run1[r], o2 = run2[r];
            run1[r] = min(o1, key);
            run2[r] = umed3(o1, key, o2);
            run3[r] = umed3(o2, key, run3[r]);
        }
    }

    float thr[4];
    #pragma unroll
    for (int r = 0; r < 4; ++r) {
        unsigned v = run1[r];
        v = min(v, (unsigned)__shfl_xor((int)v, 1));
        v = min(v, (unsigned)__shfl_xor((int)v, 2));
        v = min(v, (unsigned)__shfl_xor((int)v, 4));
        v = min(v, (unsigned)__shfl_xor((int)v, 8));
        thr[r] = __uint_as_float(v & 0xFFFFFE00u) + VQ_WINDOW;
    }

    bool f = false;
    #pragma unroll
    for (int r = 0; r < 4; ++r)
        f |= (__uint_as_float(run3[r] & 0xFFFFFE00u) <= thr[r]);
    const unsigned long long waveflag = __ballot(f);

    if (waveflag != 0ull) {
        #pragma unroll 4
        for (int nt = 0; nt < 32; ++nt) {
            bf16x8 b0 = lBf[(nt * 2 + 0) * 64 + lane];
            bf16x8 b1 = lBf[(nt * 2 + 1) * 64 + lane];
            f32x4 c = {0.0f, 0.0f, 0.0f, 0.0f};
            c = __builtin_amdgcn_mfma_f32_16x16x32_bf16(afrag[0], b0, c, 0, 0, 0);
            c = __builtin_amdgcn_mfma_f32_16x16x32_bf16(afrag[1], b1, c, 0, 0, 0);
            const float kn   = kn2p[nt * 16 + col];
            const int   kidx = nt * 16 + col;
            #pragma unroll
            for (int r = 0; r < 4; ++r) {
                float s = fmaf(m2r[r], c[r], kn);
                if (s <= thr[r]) {
                    int pix = pbase + wr * 16 + quad * 4 + r;
                    int pos = atomicAdd(&scnt[pix], 1);
                    if (pos < VQ_CAP) slist[pix][pos] = kidx;
                }
            }
        }
    } else {
        #pragma unroll
        for (int r = 0; r < 4; ++r) {
            float s1 = __uint_as_float(run1[r] & 0xFFFFFE00u);
            if (s1 <= thr[r]) {
                int pix = pbase + wr * 16 + quad * 4 + r;
                int pos = atomicAdd(&scnt[pix], 1);
                if (pos < VQ_CAP) slist[pix][pos] = (int)(run1[r] & 0x1FFu);
            }
            float s2 = __uint_as_float(run2[r] & 0xFFFFFE00u);
            if (s2 <= thr[r]) {
                int pix = pbase + wr * 16 + quad * 4 + r;
                int pos = atomicAdd(&scnt[pix], 1);
                if (pos < VQ_CAP) slist[pix][pos] = (int)(run2[r] & 0x1FFu);
            }
        }
    }
    wave_lds_fence();

    {
        const int pw   = wr * 16 + (lane >> 2);
        const int P    = pbase + pw;
        const int sub  = lane & 3;
        const int cnt  = scnt[P];
        if (cnt > 1) {
            const float* xp = xblk + pw;
            if (cnt <= VQ_CAP) {
                for (int i = sub; i < cnt; i += 4) {
                    const int k = slist[P][i];
                    const float* cr = cbn + (size_t)k * 64;
                    float dot = 0.0f;
                    #pragma unroll 8
                    for (int c = 0; c < 64; ++c)
                        dot = fmaf(xp[(size_t)c * 4096], cr[c], dot);
                    float s = fmaf(m2P, dot, kn2[k]);
                    unsigned long long key =
                        ((unsigned long long)f2ord(s) << 32) | (unsigned)k;
                    atomicMin(&spack[P], key);
                }
            } else {
                for (int k = sub; k < 512; k += 4) {
                    const float* cr = cbn + (size_t)k * 64;
                    float dot = 0.0f;
                    #pragma unroll 8
                    for (int c = 0; c < 64; ++c)
                        dot = fmaf(xp[(size_t)c * 4096], cr[c], dot);
                    float s = fmaf(m2P, dot, kn2[k]);
                    unsigned long long key =
                        ((unsigned long long)f2ord(s) << 32) | (unsigned)k;
                    atomicMin(&spack[P], key);
                }
            }
        }
    }
    wave_lds_fence();

    const int cntw = scnt[pslot];
    const int bk = (cntw == 1) ? slist[pslot][0]
                               : (int)(spack[pslot] & 0xFFFFFFFFull);

    if (quad == 0) idxout[rowid * 64 + wpix] = (float)bk;

    {
        const float4* crow = (const float4*)(cbn + (size_t)bk * 64) + quad * 4;
        float* cp = codes + ((size_t)b << 18) + (h << 6) + wpix;
        #pragma unroll
        for (int q = 0; q < 4; ++q) {
            float4 v = crow[q];
            const int c0 = quad * 16 + q * 4;
            cp[(size_t)(c0 + 0) * 4096] = v.x;
            cp[(size_t)(c0 + 1) * 4096] = v.y;
            cp[(size_t)(c0 + 2) * 4096] = v.z;
            cp[(size_t)(c0 + 3) * 4096] = v.w;
        }
    }
}

extern "C" void kernel_launch(void* const* d_in, const int* in_sizes, int n_in,
                              void* d_out, int out_size, void* d_ws, size_t ws_size,
                              hipStream_t stream) {
    const float* x  = (const float*)d_in[0];   // [32,64,64,64] fp32
    const float* cb = (const float*)d_in[1];   // [512,64] fp32

    char* ws = (char*)d_ws;
    float*          cbn  = (float*)(ws + 0);                   // 131072 B
    unsigned short* cbB  = (unsigned short*)(ws + 131072);     // 65536 B
    float*          kn2  = (float*)(ws + 196608);              // 2048 B
    float*          kn2p = (float*)(ws + 198656);              // 2048 B
    // split-path per-pixel state (131072 pixels):
    int*            pcnt  = (int*)(ws + 200704);               // 524288 B
    float*          pm2   = (float*)(ws + 724992);             // 524288 B
    unsigned short* pcand = (unsigned short*)(ws + 1249280);   // 3145728 B
    const size_t WS_NEEDED = 1249280 + 3145728;                // ~4.2 MB

    float* codes  = (float*)d_out;                             // 32*64*64*64 floats
    float* idxout = codes + (size_t)32 * 64 * 64 * 64;         // 131072 floats

    cb_prep_kernel<<<512, 64, 0, stream>>>(cb, cbn, cbB, kn2, kn2p);
    if (ws_size >= WS_NEEDED) {
        vq_scan_kernel<<<512, 1024, 0, stream>>>(x, cbB, kn2p, pcnt, pm2, pcand);
        vq_finish_kernel<<<2048, 256, 0, stream>>>(x, cbn, kn2, pcnt, pm2, pcand,
                                                   codes, idxout);
    } else {
        vq_mfma_kernel<<<512, 1024, 0, stream>>>(x, cbn, cbB, kn2, kn2p,
                                                 codes, idxout);
    }
}

// Round 11
// 116.560 us; speedup vs baseline: 1.0295x; 1.0295x over previous
//
#include <hip/hip_runtime.h>

#define VQ_EPS    1e-12f
#define VQ_WINDOW 0.01f     // >= ~14 sigma of the bf16 score error; proven R6-R10 (absmax 0)
#define VQ_CAP    12

typedef short bf16x8 __attribute__((ext_vector_type(8)));   // 8 bf16 bit-patterns = 4 VGPRs
typedef float f32x4  __attribute__((ext_vector_type(4)));

static __device__ __forceinline__ unsigned short f2bf(float f) {
    unsigned u = __float_as_uint(f);
    u += 0x7fffu + ((u >> 16) & 1u);     // RNE
    return (unsigned short)(u >> 16);
}

// Order-preserving float->uint map (handles negative exact scores).
static __device__ __forceinline__ unsigned f2ord(float f) {
    unsigned b = __float_as_uint(f);
    return (b & 0x80000000u) ? ~b : (b | 0x80000000u);
}

// Wave-local LDS fence (proven R14, absmax 0): drains this wave's DS ops and
// stops compiler reordering. Sufficient for slot traffic produced AND
// consumed by the same wave (all of scnt/slist/spack -- indices derive from
// wid only).
static __device__ __forceinline__ void wave_lds_fence() {
    asm volatile("s_waitcnt lgkmcnt(0)" ::: "memory");
}

// Single-instruction median (VOP3 v_med3_u32, GCN3+/gfx950).
static __device__ __forceinline__ unsigned umed3(unsigned a, unsigned b, unsigned c) {
    unsigned d;
    asm("v_med3_u32 %0, %1, %2, %3" : "=v"(d) : "v"(a), "v"(b), "v"(c));
    return d;
}

// Prep kernel: normalize codebook rows (fp32, mirrors F.normalize), emit:
//   cbn  [512][64] fp32      -- exact rescore + codes-gather epilogue
//   cbB  [32 ntile][2 kstep][64 lane][8] bf16 -- B-fragment-linear for
//        mfma_f32_16x16x32_bf16 (layout proven correct R5-R10)
//   kn2  [512] fp32          -- sum(cbn^2) AFTER normalization (reference rounding)
//   kn2p [512] fp32          -- kn2 + 2.0f (keeps approx scores > 0 for uint packing)
__global__ __launch_bounds__(64) void cb_prep_kernel(const float* __restrict__ cb,
                                                     float* __restrict__ cbn,
                                                     unsigned short* __restrict__ cbB,
                                                     float* __restrict__ kn2,
                                                     float* __restrict__ kn2p) {
    const int k = blockIdx.x;       // 512 codes
    const int c = threadIdx.x;      // 64 channels
    float v = cb[k * 64 + c];
    float s = v * v;
    #pragma unroll
    for (int off = 32; off > 0; off >>= 1) s += __shfl_xor(s, off, 64);
    float n = sqrtf(s);
    float cn = v / fmaxf(n, VQ_EPS);
    cbn[k * 64 + c] = cn;

    const int ntile = k >> 4, col = k & 15;
    const int ks = c >> 5, quad = (c >> 3) & 3, j = c & 7;
    cbB[(((ntile * 2 + ks) * 64) + quad * 16 + col) * 8 + j] = f2bf(cn);

    float s2 = cn * cn;
    #pragma unroll
    for (int off = 32; off > 0; off >>= 1) s2 += __shfl_xor(s2, off, 64);
    if (c == 0) { kn2[k] = s2; kn2p[k] = s2 + 2.0f; }
}

// Main kernel R21: R19 base (512 blocks x 1024 thr, 16 waves = 4 rows,
// 32 waves/CU, top-3 sorted slot tracking -- best verified, 46.4-50.0 us,
// absmax 0, 28 VGPR) with two additive changes:
//   1. EARLY EPILOGUE: pixels with cnt==1 (~60-70%, winner known at collect
//      time = slist[0]) write codes/idx immediately after the B1 fence --
//      their 64B-sector stores drain UNDER the cnt>1 pixels' rescore
//      latency chains instead of in a burst after them. The late epilogue
//      covers only cnt>1 pixels. Pure reordering: same values, all slot
//      reads after the wave-local fence (R20's split showed the tail phases
//      must overlap IN-KERNEL where x is L2-hot, not across kernels).
//   2. Scan unroll 4 -> 8 (28 VGPR leaves headroom; deeper ds_read pipeline).
// R18 lesson: no big per-thread arrays; VGPR must stay <= 64 for 8 w/SIMD.
// Safety recipe (R8/R9/R14, proven): shfls/ballot only in uniform code;
// slot init + candidate pushes wave-owned; rescore per-lane only;
// wave-local fences for same-wave slot traffic; B0 covers staging.
__global__ __launch_bounds__(1024, 8) void vq_mfma_kernel(const float* __restrict__ x,
                                                      const float* __restrict__ cbn,
                                                      const unsigned short* __restrict__ cbB,
                                                      const float* __restrict__ kn2,
                                                      const float* __restrict__ kn2p,
                                                      float* __restrict__ codes,
                                                      float* __restrict__ idxout) {
    __shared__ __align__(16) unsigned short lcb[32768];   // 64 KB staged cbB
    __shared__ unsigned long long spack[256];             // 2 KB
    __shared__ int slist[256][VQ_CAP];                    // 12 KB
    __shared__ int scnt[256];                             // 1 KB   -> 79 KB total

    const int t    = threadIdx.x;
    const int lane = t & 63;
    const int wid  = t >> 6;          // 0..15
    const int col  = lane & 15;
    const int quad = lane >> 4;
    const int wr   = wid & 3;         // wave within its row
    const int rsel = wid >> 2;        // which of the block's 4 rows
    const int wpix = wr * 16 + col;   // col-group's pixel (w coordinate)
    const int pbase = rsel * 64;      // LDS pixel-slot base for this row
    const int pslot = pbase + wpix;

    const int rowid = blockIdx.x * 4 + rsel;   // 0..2047 = (b,h)
    const int b = rowid >> 6;
    const int h = rowid & 63;
    const float* xblk = x + ((size_t)b << 18) + (h << 6);   // + c*4096 + w

    if (quad == 0) { scnt[pslot] = 0; spack[pslot] = 0xFFFFFFFFFFFFFFFFull; }

    // ---- A fragments: 16 channels of this lane's pixel, from global ----
    // (issued first so the HBM gather latency hides under the cbB staging)
    float xv[16];
    #pragma unroll
    for (int ks = 0; ks < 2; ++ks)
        #pragma unroll
        for (int j = 0; j < 8; ++j)
            xv[ks * 8 + j] = xblk[(size_t)(ks * 32 + quad * 8 + j) * 4096 + wpix];

    // ---- stage cbB -> LDS: 1024 thr x 4 x 16 B, linear, coalesced ----
    {
        const uint4* g4 = (const uint4*)cbB;
        uint4*       l4 = (uint4*)lcb;
        #pragma unroll
        for (int r = 0; r < 4; ++r) l4[r * 1024 + t] = g4[r * 1024 + t];
    }

    float ssp = 0.0f;
    #pragma unroll
    for (int i = 0; i < 16; ++i) ssp = fmaf(xv[i], xv[i], ssp);
    ssp += __shfl_xor(ssp, 16);      // uniform code: all 64 lanes execute
    ssp += __shfl_xor(ssp, 32);
    const float m2a = -2.0f * (1.0f / fmaxf(sqrtf(ssp), VQ_EPS));
    float m2r[4];
    #pragma unroll
    for (int r = 0; r < 4; ++r) m2r[r] = __shfl(m2a, quad * 4 + r);  // uniform
    const float m2P = __shfl(m2a, lane >> 2);   // uniform: m2 of rescore pixel

    bf16x8 afrag[2];
    #pragma unroll
    for (int ks = 0; ks < 2; ++ks)
        #pragma unroll
        for (int j = 0; j < 8; ++j)
            ((unsigned short*)&afrag[ks])[j] = f2bf(xv[ks * 8 + j]);

    __syncthreads();   // B0: staged cbB (and slot init) visible to all 16 waves

    const bf16x8* lBf = (const bf16x8*)lcb;

    // ---- pass 1: MFMA scan from LDS, sorted top-3 keys per (lane,r) slot ----
    unsigned run1[4] = {0xFFFFFFFFu, 0xFFFFFFFFu, 0xFFFFFFFFu, 0xFFFFFFFFu};
    unsigned run2[4] = {0xFFFFFFFFu, 0xFFFFFFFFu, 0xFFFFFFFFu, 0xFFFFFFFFu};
    unsigned run3[4] = {0xFFFFFFFFu, 0xFFFFFFFFu, 0xFFFFFFFFu, 0xFFFFFFFFu};
    #pragma unroll 8
    for (int nt = 0; nt < 32; ++nt) {
        bf16x8 b0 = lBf[(nt * 2 + 0) * 64 + lane];     // ds_read_b128, conflict-free
        bf16x8 b1 = lBf[(nt * 2 + 1) * 64 + lane];
        f32x4 c = {0.0f, 0.0f, 0.0f, 0.0f};
        c = __builtin_amdgcn_mfma_f32_16x16x32_bf16(afrag[0], b0, c, 0, 0, 0);
        c = __builtin_amdgcn_mfma_f32_16x16x32_bf16(afrag[1], b1, c, 0, 0, 0);
        const float    kn   = kn2p[nt * 16 + col];     // L1-hot
        const unsigned kidx = (unsigned)(nt * 16 + col);
        #pragma unroll
        for (int r = 0; r < 4; ++r) {
            float s = fmaf(m2r[r], c[r], kn);          // (~0.6, 5.2) -> uint-orderable
            unsigned key = (__float_as_uint(s) & 0xFFFFFE00u) | kidx;  // 9-bit k field
            unsigned o1 = run1[r], o2 = run2[r];
            run1[r] = min(o1, key);
            run2[r] = umed3(o1, key, o2);              // sorted-insert rank 2
            run3[r] = umed3(o2, key, run3[r]);         // sorted-insert rank 3
        }
    }

    // ---- thresholds: cross-lane min within each 16-lane col group (uniform) ----
    float thr[4];
    #pragma unroll
    for (int r = 0; r < 4; ++r) {
        unsigned v = run1[r];
        v = min(v, (unsigned)__shfl_xor((int)v, 1));
        v = min(v, (unsigned)__shfl_xor((int)v, 2));
        v = min(v, (unsigned)__shfl_xor((int)v, 4));
        v = min(v, (unsigned)__shfl_xor((int)v, 8));
        thr[r] = __uint_as_float(v & 0xFFFFFE00u) + VQ_WINDOW;
    }

    // ---- wave flag: any slot whose 3rd-best is within threshold? (uniform) ----
    // If not, every in-window code in every slot is among ranks 1-2, which
    // are pushed straight from registers below.
    bool f = false;
    #pragma unroll
    for (int r = 0; r < 4; ++r)
        f |= (__uint_as_float(run3[r] & 0xFFFFFE00u) <= thr[r]);
    const unsigned long long waveflag = __ballot(f);   // uniform code

    if (waveflag != 0ull) {
        // ---- fallback pass 2 (rare): bit-identical full recompute ----
        #pragma unroll 4
        for (int nt = 0; nt < 32; ++nt) {
            bf16x8 b0 = lBf[(nt * 2 + 0) * 64 + lane];
            bf16x8 b1 = lBf[(nt * 2 + 1) * 64 + lane];
            f32x4 c = {0.0f, 0.0f, 0.0f, 0.0f};
            c = __builtin_amdgcn_mfma_f32_16x16x32_bf16(afrag[0], b0, c, 0, 0, 0);
            c = __builtin_amdgcn_mfma_f32_16x16x32_bf16(afrag[1], b1, c, 0, 0, 0);
            const float kn   = kn2p[nt * 16 + col];
            const int   kidx = nt * 16 + col;
            #pragma unroll
            for (int r = 0; r < 4; ++r) {
                float s = fmaf(m2r[r], c[r], kn);
                if (s <= thr[r]) {
                    int pix = pbase + wr * 16 + quad * 4 + r;   // wave-owned pixel
                    int pos = atomicAdd(&scnt[pix], 1);
                    if (pos < VQ_CAP) slist[pix][pos] = kidx;
                }
            }
        }
    } else {
        // ---- fast path: push in-window ranks 1 AND 2 from registers ----
        #pragma unroll
        for (int r = 0; r < 4; ++r) {
            float s1 = __uint_as_float(run1[r] & 0xFFFFFE00u);
            if (s1 <= thr[r]) {
                int pix = pbase + wr * 16 + quad * 4 + r;       // wave-owned pixel
                int pos = atomicAdd(&scnt[pix], 1);
                if (pos < VQ_CAP) slist[pix][pos] = (int)(run1[r] & 0x1FFu);
            }
            float s2 = __uint_as_float(run2[r] & 0xFFFFFE00u);
            if (s2 <= thr[r]) {
                int pix = pbase + wr * 16 + quad * 4 + r;
                int pos = atomicAdd(&scnt[pix], 1);
                if (pos < VQ_CAP) slist[pix][pos] = (int)(run2[r] & 0x1FFu);
            }
        }
    }
    wave_lds_fence();   // B1 (wave-local): slot traffic above is same-wave only

    // ---- EARLY epilogue: cnt==1 pixels write now; stores drain under the
    //      rescore latency of the cnt>1 pixels. Winner = slist[0], known
    //      without rescore. Same-wave data, fence above. ----
    {
        const int cntw = scnt[pslot];
        if (cntw == 1) {
            const int bk = slist[pslot][0];
            if (quad == 0) idxout[rowid * 64 + wpix] = (float)bk;
            const float4* crow = (const float4*)(cbn + (size_t)bk * 64) + quad * 4;
            float* cp = codes + ((size_t)b << 18) + (h << 6) + wpix;
            #pragma unroll
            for (int q = 0; q < 4; ++q) {
                float4 v = crow[q];
                const int c0 = quad * 16 + q * 4;
                cp[(size_t)(c0 + 0) * 4096] = v.x;
                cp[(size_t)(c0 + 1) * 4096] = v.y;
                cp[(size_t)(c0 + 2) * 4096] = v.z;
                cp[(size_t)(c0 + 3) * 4096] = v.w;
            }
        }
    }

    // ---- exact fp32 rescore: 4 lanes/pixel, per-lane only (no shfl here) ----
    {
        const int pw   = wr * 16 + (lane >> 2);    // this lane's rescore pixel (w)
        const int P    = pbase + pw;               // its LDS slot
        const int sub  = lane & 3;
        const int cnt  = scnt[P];
        if (cnt > 1) {
            const float* xp = xblk + pw;
            if (cnt <= VQ_CAP) {
                for (int i = sub; i < cnt; i += 4) {
                    const int k = slist[P][i];
                    const float* cr = cbn + (size_t)k * 64;
                    float dot = 0.0f;
                    #pragma unroll 8
                    for (int c = 0; c < 64; ++c)
                        dot = fmaf(xp[(size_t)c * 4096], cr[c], dot);  // R1 order
                    float s = fmaf(m2P, dot, kn2[k]);
                    unsigned long long key =
                        ((unsigned long long)f2ord(s) << 32) | (unsigned)k;
                    atomicMin(&spack[P], key);
                }
            } else {   // pathological overflow: exact scan of all codes
                for (int k = sub; k < 512; k += 4) {
                    const float* cr = cbn + (size_t)k * 64;
                    float dot = 0.0f;
                    #pragma unroll 8
                    for (int c = 0; c < 64; ++c)
                        dot = fmaf(xp[(size_t)c * 4096], cr[c], dot);
                    float s = fmaf(m2P, dot, kn2[k]);
                    unsigned long long key =
                        ((unsigned long long)f2ord(s) << 32) | (unsigned)k;
                    atomicMin(&spack[P], key);
                }
            }
        }
    }
    wave_lds_fence();   // B2 (wave-local): rescore results are same-wave too

    // ---- LATE epilogue: only cnt>1 pixels (winner from packed rescore keys;
    //      ties break to smallest k) ----
    {
        const int cntw = scnt[pslot];
        if (cntw > 1) {
            const int bk = (int)(spack[pslot] & 0xFFFFFFFFull);
            if (quad == 0) idxout[rowid * 64 + wpix] = (float)bk;
            const float4* crow = (const float4*)(cbn + (size_t)bk * 64) + quad * 4;
            float* cp = codes + ((size_t)b << 18) + (h << 6) + wpix;
            #pragma unroll
            for (int q = 0; q < 4; ++q) {
                float4 v = crow[q];
                const int c0 = quad * 16 + q * 4;
                cp[(size_t)(c0 + 0) * 4096] = v.x;
                cp[(size_t)(c0 + 1) * 4096] = v.y;
                cp[(size_t)(c0 + 2) * 4096] = v.z;
                cp[(size_t)(c0 + 3) * 4096] = v.w;
            }
        }
    }
}

extern "C" void kernel_launch(void* const* d_in, const int* in_sizes, int n_in,
                              void* d_out, int out_size, void* d_ws, size_t ws_size,
                              hipStream_t stream) {
    const float* x  = (const float*)d_in[0];   // [32,64,64,64] fp32
    const float* cb = (const float*)d_in[1];   // [512,64] fp32

    float*          cbn  = (float*)d_ws;                       // 128 KB
    unsigned short* cbB  = (unsigned short*)(cbn + 512 * 64);  // 64 KB (frag-linear bf16)
    float*          kn2  = (float*)(cbB + 32768);              // 2 KB
    float*          kn2p = kn2 + 512;                          // 2 KB

    float* codes  = (float*)d_out;                             // 32*64*64*64 floats
    float* idxout = codes + (size_t)32 * 64 * 64 * 64;         // 131072 floats

    cb_prep_kernel<<<512, 64, 0, stream>>>(cb, cbn, cbB, kn2, kn2p);
    vq_mfma_kernel<<<512, 1024, 0, stream>>>(x, cbn, cbB, kn2, kn2p, codes, idxout);
}

// Round 12
// 111.860 us; speedup vs baseline: 1.0728x; 1.0420x over previous
//
#include <hip/hip_runtime.h>

#define VQ_EPS    1e-12f
#define VQ_WINDOW 0.01f     // >= ~14 sigma of the bf16 score error; proven R6-R10 (absmax 0)
#define VQ_CAP    12

typedef short bf16x8 __attribute__((ext_vector_type(8)));   // 8 bf16 bit-patterns = 4 VGPRs
typedef float f32x4  __attribute__((ext_vector_type(4)));

static __device__ __forceinline__ unsigned short f2bf(float f) {
    unsigned u = __float_as_uint(f);
    u += 0x7fffu + ((u >> 16) & 1u);     // RNE
    return (unsigned short)(u >> 16);
}

// Order-preserving float->uint map (handles negative exact scores).
static __device__ __forceinline__ unsigned f2ord(float f) {
    unsigned b = __float_as_uint(f);
    return (b & 0x80000000u) ? ~b : (b | 0x80000000u);
}

// Wave-local LDS fence (proven R14, absmax 0): drains this wave's DS ops and
// stops compiler reordering. Sufficient for slot traffic produced AND
// consumed by the same wave (all of scnt/slist/spack -- indices derive from
// wid only).
static __device__ __forceinline__ void wave_lds_fence() {
    asm volatile("s_waitcnt lgkmcnt(0)" ::: "memory");
}

// Single-instruction median (VOP3 v_med3_u32, GCN3+/gfx950).
static __device__ __forceinline__ unsigned umed3(unsigned a, unsigned b, unsigned c) {
    unsigned d;
    asm("v_med3_u32 %0, %1, %2, %3" : "=v"(d) : "v"(a), "v"(b), "v"(c));
    return d;
}

// Prep kernel: normalize codebook rows (fp32, mirrors F.normalize), emit:
//   cbn  [512][64] fp32      -- exact rescore + codes-gather epilogue
//   cbB  [32 ntile][2 kstep][64 lane][8] bf16 -- B-fragment-linear for
//        mfma_f32_16x16x32_bf16 (layout proven correct R5-R10)
//   kn2  [512] fp32          -- sum(cbn^2) AFTER normalization (reference rounding)
//   kn2p [512] fp32          -- kn2 + 2.0f (keeps approx scores > 0 for uint packing)
__global__ __launch_bounds__(64) void cb_prep_kernel(const float* __restrict__ cb,
                                                     float* __restrict__ cbn,
                                                     unsigned short* __restrict__ cbB,
                                                     float* __restrict__ kn2,
                                                     float* __restrict__ kn2p) {
    const int k = blockIdx.x;       // 512 codes
    const int c = threadIdx.x;      // 64 channels
    float v = cb[k * 64 + c];
    float s = v * v;
    #pragma unroll
    for (int off = 32; off > 0; off >>= 1) s += __shfl_xor(s, off, 64);
    float n = sqrtf(s);
    float cn = v / fmaxf(n, VQ_EPS);
    cbn[k * 64 + c] = cn;

    const int ntile = k >> 4, col = k & 15;
    const int ks = c >> 5, quad = (c >> 3) & 3, j = c & 7;
    cbB[(((ntile * 2 + ks) * 64) + quad * 16 + col) * 8 + j] = f2bf(cn);

    float s2 = cn * cn;
    #pragma unroll
    for (int off = 32; off > 0; off >>= 1) s2 += __shfl_xor(s2, off, 64);
    if (c == 0) { kn2[k] = s2; kn2p[k] = s2 + 2.0f; }
}

// Main kernel R22 = R19 verbatim (the session's best verified configuration:
// 115.65 us harness / 46.4-50.0 us kernel, absmax 0, 28 VGPR).
// 512 blocks x 1024 thr, 16 waves = 4 rows, 32 waves/CU, LDS-staged cbB,
// sorted top-3 slot tracking (min + 2x v_med3_u32 per score -- same 3-op
// cost as top-2), rank-1/2 register fast path, 3rd-best-in-window fallback.
// Reverted from R21: early cnt==1 epilogue (WRITE 35->54 MB sector-split
// amplification, +4 us) and the confounded unroll-8.
// Closed structural arcs (do not revisit): cross-kernel split (R20, cold-x
// re-read), 2-row fusion (R16/R17 TLP loss; R18 VGPR spill), 2-generation
// grids (R12 < R13), barrier relaxation (R14 neutral -- kept as fences).
// Safety recipe (R8/R9/R14, proven): shfls/ballot only in uniform code;
// slot init + candidate pushes wave-owned; rescore per-lane only;
// wave-local fences for same-wave slot traffic; B0 covers staging.
__global__ __launch_bounds__(1024, 8) void vq_mfma_kernel(const float* __restrict__ x,
                                                      const float* __restrict__ cbn,
                                                      const unsigned short* __restrict__ cbB,
                                                      const float* __restrict__ kn2,
                                                      const float* __restrict__ kn2p,
                                                      float* __restrict__ codes,
                                                      float* __restrict__ idxout) {
    __shared__ __align__(16) unsigned short lcb[32768];   // 64 KB staged cbB
    __shared__ unsigned long long spack[256];             // 2 KB
    __shared__ int slist[256][VQ_CAP];                    // 12 KB
    __shared__ int scnt[256];                             // 1 KB   -> 79 KB total

    const int t    = threadIdx.x;
    const int lane = t & 63;
    const int wid  = t >> 6;          // 0..15
    const int col  = lane & 15;
    const int quad = lane >> 4;
    const int wr   = wid & 3;         // wave within its row
    const int rsel = wid >> 2;        // which of the block's 4 rows
    const int wpix = wr * 16 + col;   // col-group's pixel (w coordinate)
    const int pbase = rsel * 64;      // LDS pixel-slot base for this row
    const int pslot = pbase + wpix;

    const int rowid = blockIdx.x * 4 + rsel;   // 0..2047 = (b,h)
    const int b = rowid >> 6;
    const int h = rowid & 63;
    const float* xblk = x + ((size_t)b << 18) + (h << 6);   // + c*4096 + w

    if (quad == 0) { scnt[pslot] = 0; spack[pslot] = 0xFFFFFFFFFFFFFFFFull; }

    // ---- A fragments: 16 channels of this lane's pixel, from global ----
    // (issued first so the HBM gather latency hides under the cbB staging)
    float xv[16];
    #pragma unroll
    for (int ks = 0; ks < 2; ++ks)
        #pragma unroll
        for (int j = 0; j < 8; ++j)
            xv[ks * 8 + j] = xblk[(size_t)(ks * 32 + quad * 8 + j) * 4096 + wpix];

    // ---- stage cbB -> LDS: 1024 thr x 4 x 16 B, linear, coalesced ----
    {
        const uint4* g4 = (const uint4*)cbB;
        uint4*       l4 = (uint4*)lcb;
        #pragma unroll
        for (int r = 0; r < 4; ++r) l4[r * 1024 + t] = g4[r * 1024 + t];
    }

    float ssp = 0.0f;
    #pragma unroll
    for (int i = 0; i < 16; ++i) ssp = fmaf(xv[i], xv[i], ssp);
    ssp += __shfl_xor(ssp, 16);      // uniform code: all 64 lanes execute
    ssp += __shfl_xor(ssp, 32);
    const float m2a = -2.0f * (1.0f / fmaxf(sqrtf(ssp), VQ_EPS));
    float m2r[4];
    #pragma unroll
    for (int r = 0; r < 4; ++r) m2r[r] = __shfl(m2a, quad * 4 + r);  // uniform
    const float m2P = __shfl(m2a, lane >> 2);   // uniform: m2 of rescore pixel

    bf16x8 afrag[2];
    #pragma unroll
    for (int ks = 0; ks < 2; ++ks)
        #pragma unroll
        for (int j = 0; j < 8; ++j)
            ((unsigned short*)&afrag[ks])[j] = f2bf(xv[ks * 8 + j]);

    __syncthreads();   // B0: staged cbB (and slot init) visible to all 16 waves

    const bf16x8* lBf = (const bf16x8*)lcb;

    // ---- pass 1: MFMA scan from LDS, sorted top-3 keys per (lane,r) slot ----
    unsigned run1[4] = {0xFFFFFFFFu, 0xFFFFFFFFu, 0xFFFFFFFFu, 0xFFFFFFFFu};
    unsigned run2[4] = {0xFFFFFFFFu, 0xFFFFFFFFu, 0xFFFFFFFFu, 0xFFFFFFFFu};
    unsigned run3[4] = {0xFFFFFFFFu, 0xFFFFFFFFu, 0xFFFFFFFFu, 0xFFFFFFFFu};
    #pragma unroll 4
    for (int nt = 0; nt < 32; ++nt) {
        bf16x8 b0 = lBf[(nt * 2 + 0) * 64 + lane];     // ds_read_b128, conflict-free
        bf16x8 b1 = lBf[(nt * 2 + 1) * 64 + lane];
        f32x4 c = {0.0f, 0.0f, 0.0f, 0.0f};
        c = __builtin_amdgcn_mfma_f32_16x16x32_bf16(afrag[0], b0, c, 0, 0, 0);
        c = __builtin_amdgcn_mfma_f32_16x16x32_bf16(afrag[1], b1, c, 0, 0, 0);
        const float    kn   = kn2p[nt * 16 + col];     // L1-hot
        const unsigned kidx = (unsigned)(nt * 16 + col);
        #pragma unroll
        for (int r = 0; r < 4; ++r) {
            float s = fmaf(m2r[r], c[r], kn);          // (~0.6, 5.2) -> uint-orderable
            unsigned key = (__float_as_uint(s) & 0xFFFFFE00u) | kidx;  // 9-bit k field
            unsigned o1 = run1[r], o2 = run2[r];
            run1[r] = min(o1, key);
            run2[r] = umed3(o1, key, o2);              // sorted-insert rank 2
            run3[r] = umed3(o2, key, run3[r]);         // sorted-insert rank 3
        }
    }

    // ---- thresholds: cross-lane min within each 16-lane col group (uniform) ----
    float thr[4];
    #pragma unroll
    for (int r = 0; r < 4; ++r) {
        unsigned v = run1[r];
        v = min(v, (unsigned)__shfl_xor((int)v, 1));
        v = min(v, (unsigned)__shfl_xor((int)v, 2));
        v = min(v, (unsigned)__shfl_xor((int)v, 4));
        v = min(v, (unsigned)__shfl_xor((int)v, 8));
        thr[r] = __uint_as_float(v & 0xFFFFFE00u) + VQ_WINDOW;
    }

    // ---- wave flag: any slot whose 3rd-best is within threshold? (uniform) ----
    // If not, every in-window code in every slot is among ranks 1-2, which
    // are pushed straight from registers below.
    bool f = false;
    #pragma unroll
    for (int r = 0; r < 4; ++r)
        f |= (__uint_as_float(run3[r] & 0xFFFFFE00u) <= thr[r]);
    const unsigned long long waveflag = __ballot(f);   // uniform code

    if (waveflag != 0ull) {
        // ---- fallback pass 2 (rare): bit-identical full recompute ----
        #pragma unroll 4
        for (int nt = 0; nt < 32; ++nt) {
            bf16x8 b0 = lBf[(nt * 2 + 0) * 64 + lane];
            bf16x8 b1 = lBf[(nt * 2 + 1) * 64 + lane];
            f32x4 c = {0.0f, 0.0f, 0.0f, 0.0f};
            c = __builtin_amdgcn_mfma_f32_16x16x32_bf16(afrag[0], b0, c, 0, 0, 0);
            c = __builtin_amdgcn_mfma_f32_16x16x32_bf16(afrag[1], b1, c, 0, 0, 0);
            const float kn   = kn2p[nt * 16 + col];
            const int   kidx = nt * 16 + col;
            #pragma unroll
            for (int r = 0; r < 4; ++r) {
                float s = fmaf(m2r[r], c[r], kn);
                if (s <= thr[r]) {
                    int pix = pbase + wr * 16 + quad * 4 + r;   // wave-owned pixel
                    int pos = atomicAdd(&scnt[pix], 1);
                    if (pos < VQ_CAP) slist[pix][pos] = kidx;
                }
            }
        }
    } else {
        // ---- fast path: push in-window ranks 1 AND 2 from registers ----
        #pragma unroll
        for (int r = 0; r < 4; ++r) {
            float s1 = __uint_as_float(run1[r] & 0xFFFFFE00u);
            if (s1 <= thr[r]) {
                int pix = pbase + wr * 16 + quad * 4 + r;       // wave-owned pixel
                int pos = atomicAdd(&scnt[pix], 1);
                if (pos < VQ_CAP) slist[pix][pos] = (int)(run1[r] & 0x1FFu);
            }
            float s2 = __uint_as_float(run2[r] & 0xFFFFFE00u);
            if (s2 <= thr[r]) {
                int pix = pbase + wr * 16 + quad * 4 + r;
                int pos = atomicAdd(&scnt[pix], 1);
                if (pos < VQ_CAP) slist[pix][pos] = (int)(run2[r] & 0x1FFu);
            }
        }
    }
    wave_lds_fence();   // B1 (wave-local): slot traffic above is same-wave only

    // ---- exact fp32 rescore: 4 lanes/pixel, per-lane only (no shfl here) ----
    {
        const int pw   = wr * 16 + (lane >> 2);    // this lane's rescore pixel (w)
        const int P    = pbase + pw;               // its LDS slot
        const int sub  = lane & 3;
        const int cnt  = scnt[P];
        if (cnt > 1) {
            const float* xp = xblk + pw;
            if (cnt <= VQ_CAP) {
                for (int i = sub; i < cnt; i += 4) {
                    const int k = slist[P][i];
                    const float* cr = cbn + (size_t)k * 64;
                    float dot = 0.0f;
                    #pragma unroll 8
                    for (int c = 0; c < 64; ++c)
                        dot = fmaf(xp[(size_t)c * 4096], cr[c], dot);  // R1 order
                    float s = fmaf(m2P, dot, kn2[k]);
                    unsigned long long key =
                        ((unsigned long long)f2ord(s) << 32) | (unsigned)k;
                    atomicMin(&spack[P], key);
                }
            } else {   // pathological overflow: exact scan of all codes
                for (int k = sub; k < 512; k += 4) {
                    const float* cr = cbn + (size_t)k * 64;
                    float dot = 0.0f;
                    #pragma unroll 8
                    for (int c = 0; c < 64; ++c)
                        dot = fmaf(xp[(size_t)c * 4096], cr[c], dot);
                    float s = fmaf(m2P, dot, kn2[k]);
                    unsigned long long key =
                        ((unsigned long long)f2ord(s) << 32) | (unsigned)k;
                    atomicMin(&spack[P], key);
                }
            }
        }
    }
    wave_lds_fence();   // B2 (wave-local): rescore results are same-wave too

    // ---- winner (packed key ties break to smallest k; cnt==1 fast path) ----
    const int cntw = scnt[pslot];
    const int bk = (cntw == 1) ? slist[pslot][0]
                               : (int)(spack[pslot] & 0xFFFFFFFFull);

    if (quad == 0) idxout[rowid * 64 + wpix] = (float)bk;

    // ---- epilogue: codes[b, :, h, wpix] = cbn[bk, :]; lane writes channels
    //      quad*16 .. quad*16+15. Single fused pass: splitting this by
    //      cnt fragments 64B sectors -> +19 MB WRITE (R21 lesson). ----
    {
        const float4* crow = (const float4*)(cbn + (size_t)bk * 64) + quad * 4;
        float* cp = codes + ((size_t)b << 18) + (h << 6) + wpix;
        #pragma unroll
        for (int q = 0; q < 4; ++q) {
            float4 v = crow[q];
            const int c0 = quad * 16 + q * 4;
            cp[(size_t)(c0 + 0) * 4096] = v.x;
            cp[(size_t)(c0 + 1) * 4096] = v.y;
            cp[(size_t)(c0 + 2) * 4096] = v.z;
            cp[(size_t)(c0 + 3) * 4096] = v.w;
        }
    }
}

extern "C" void kernel_launch(void* const* d_in, const int* in_sizes, int n_in,
                              void* d_out, int out_size, void* d_ws, size_t ws_size,
                              hipStream_t stream) {
    const float* x  = (const float*)d_in[0];   // [32,64,64,64] fp32
    const float* cb = (const float*)d_in[1];   // [512,64] fp32

    float*          cbn  = (float*)d_ws;                       // 128 KB
    unsigned short* cbB  = (unsigned short*)(cbn + 512 * 64);  // 64 KB (frag-linear bf16)
    float*          kn2  = (float*)(cbB + 32768);              // 2 KB
    float*          kn2p = kn2 + 512;                          // 2 KB

    float* codes  = (float*)d_out;                             // 32*64*64*64 floats
    float* idxout = codes + (size_t)32 * 64 * 64 * 64;         // 131072 floats

    cb_prep_kernel<<<512, 64, 0, stream>>>(cb, cbn, cbB, kn2, kn2p);
    vq_mfma_kernel<<<512, 1024, 0, stream>>>(x, cbn, cbB, kn2, kn2p, codes, idxout);
}